// Round 1
// baseline (462.756 us; speedup 1.0000x reference)
//
#include <hip/hip_runtime.h>

// Bahdanau attention, MI355X. B=32, S=4096, D=U=512, fp32 in/out.
// score GEMM (68.7 GFLOP) via bf16 MFMA 16x16x32; proj_v never materialized.
#define NB 32
#define NS 4096
#define ND 512
#define NU 512

typedef __attribute__((ext_vector_type(8))) __bf16 bf16x8;
typedef __attribute__((ext_vector_type(8))) short short8;
typedef __attribute__((ext_vector_type(4))) float f32x4;

union Cvt8 { __bf16 h[8]; short8 s8; };

// ---- K0a: pack W1 (f32 [D][U]) -> bf16 MFMA B-fragment order ----
// W1f[ks][ct][lane][j]: k = ks*32 + (lane>>4)*8 + j, u = ct*16 + (lane&15)
// so a wave's B-frag load is lane-contiguous 16B (1 KB/wave, L2-resident).
__global__ void pack_w1_kernel(const float* __restrict__ W1, __bf16* __restrict__ W1f) {
  int idx = blockIdx.x * 256 + threadIdx.x;   // 0..32767 = [16 ks][32 ct][64 lane]
  int l  = idx & 63;
  int ct = (idx >> 6) & 31;
  int ks = idx >> 11;
  int col   = ct * 16 + (l & 15);
  int kbase = ks * 32 + (l >> 4) * 8;
  Cvt8 u;
#pragma unroll
  for (int j = 0; j < 8; ++j) u.h[j] = (__bf16)W1[(size_t)(kbase + j) * NU + col];
  *reinterpret_cast<short8*>(W1f + (size_t)idx * 8) = u.s8;
}

// ---- K0b: pq[b][u] = query[b]@W2[:,u] + b2[u] + b1[u]  (fp32, tiny) ----
__global__ void proj_query_kernel(const float* __restrict__ query, const float* __restrict__ W2,
                                  const float* __restrict__ b2, const float* __restrict__ b1,
                                  float* __restrict__ pq) {
  int b = blockIdx.y;
  int u = blockIdx.x * 256 + threadIdx.x;
  const float* q = query + (size_t)b * ND;
  float acc = b2[u] + b1[u];
  for (int k = 0; k < ND; ++k) acc += q[k] * W2[(size_t)k * NU + u];
  pq[(size_t)b * NU + u] = acc;
}

// ---- K2: score[b][s] = sum_u tanh(values[b,s,:]@W1[:,u] + pq[b][u]) * V[u] ----
// 64 s-rows per block, 4 waves, each wave owns a 64x64 output chunk per n-iter.
// values tile staged fp32->bf16 in 64 KB LDS, XOR-swizzled (row stride 1024 B
// would otherwise be a 16-way bank conflict on ds_read_b128: G4 / T2).
__global__ __launch_bounds__(256, 2)
void score_kernel(const float* __restrict__ values, const __bf16* __restrict__ W1f,
                  const float* __restrict__ pq, const float* __restrict__ V,
                  float* __restrict__ scoreW) {
  __shared__ short8 lds_s8[4096];             // 64 KB: bf16 [64 rows][512 k], swizzled
  char* ldsb = (char*)lds_s8;

  int bid = blockIdx.x;                       // 2048 = 32 b * 64 tiles
  int b = bid >> 6;
  int s0 = (bid & 63) * 64;
  int tid = threadIdx.x;
  int l = tid & 63;
  int w = tid >> 6;
  int lane_col = l & 15;                      // MFMA col / A-row selector
  int lane_k8  = l >> 4;                      // MFMA k-group / D-row group

  // stage values[b, s0:s0+64, :] -> LDS bf16 (coalesced 32 B/lane global reads)
  const float* vbase = values + ((size_t)b * NS + s0) * ND;
  for (int it = 0; it < 16; ++it) {
    int idx = it * 256 + tid;                 // [row 0..63][c8 0..63] (8 floats each)
    int row = idx >> 6;
    int c8  = idx & 63;
    const float4* src = reinterpret_cast<const float4*>(vbase + (size_t)row * ND + c8 * 8);
    float4 f0 = src[0], f1 = src[1];
    Cvt8 u;
    u.h[0] = (__bf16)f0.x; u.h[1] = (__bf16)f0.y; u.h[2] = (__bf16)f0.z; u.h[3] = (__bf16)f0.w;
    u.h[4] = (__bf16)f1.x; u.h[5] = (__bf16)f1.y; u.h[6] = (__bf16)f1.z; u.h[7] = (__bf16)f1.w;
    int boff = row * 1024 + ((c8 * 16) ^ ((row & 7) << 4));
    *reinterpret_cast<short8*>(ldsb + boff) = u.s8;
  }
  __syncthreads();

  float partial[4][4];                        // [rf][r] score partials, col = lane_col
#pragma unroll
  for (int rf = 0; rf < 4; ++rf)
#pragma unroll
    for (int r = 0; r < 4; ++r) partial[rf][r] = 0.f;

  const f32x4 zero4 = {0.f, 0.f, 0.f, 0.f};
  for (int nb = 0; nb < 2; ++nb) {
    int colbase = nb * 256 + w * 64;
    int ctbase  = colbase >> 4;
    f32x4 acc[4][4];
#pragma unroll
    for (int rf = 0; rf < 4; ++rf)
#pragma unroll
      for (int cf = 0; cf < 4; ++cf) acc[rf][cf] = zero4;

    for (int ks = 0; ks < 16; ++ks) {
      bf16x8 a[4];
      int kbyte = ks * 64 + lane_k8 * 16;
#pragma unroll
      for (int rf = 0; rf < 4; ++rf) {
        int row = rf * 16 + lane_col;         // A: row = lane&15, 8 consecutive k
        a[rf] = *reinterpret_cast<const bf16x8*>(ldsb + row * 1024 + (kbyte ^ ((row & 7) << 4)));
      }
      bf16x8 bb[4];
#pragma unroll
      for (int cf = 0; cf < 4; ++cf)          // B-frags straight from L2 (packed)
        bb[cf] = *reinterpret_cast<const bf16x8*>(W1f + ((size_t)(ks * 32 + ctbase + cf) * 64 + l) * 8);
#pragma unroll
      for (int cf = 0; cf < 4; ++cf)
#pragma unroll
        for (int rf = 0; rf < 4; ++rf)
          acc[rf][cf] = __builtin_amdgcn_mfma_f32_16x16x32_bf16(a[rf], bb[cf], acc[rf][cf], 0, 0, 0);
    }

    // epilogue: tanh(proj + pq) * V, accumulate per-row partials
#pragma unroll
    for (int cf = 0; cf < 4; ++cf) {
      int col = colbase + cf * 16 + lane_col; // C/D: col = lane&15 (m89-verified)
      float pqv = pq[(size_t)b * NU + col];
      float Vv  = V[col];
#pragma unroll
      for (int rf = 0; rf < 4; ++rf)
#pragma unroll
        for (int r = 0; r < 4; ++r) {
          float t = tanhf(acc[rf][cf][r] + pqv);
          partial[rf][r] += t * Vv;
        }
    }
  }

  // reduce over the 16 columns held across lanes sharing l>>4
#pragma unroll
  for (int off = 1; off < 16; off <<= 1)
#pragma unroll
    for (int rf = 0; rf < 4; ++rf)
#pragma unroll
      for (int r = 0; r < 4; ++r) partial[rf][r] += __shfl_xor(partial[rf][r], off);

  __syncthreads();                            // all waves done reading values LDS
  float* sbuf = (float*)ldsb;                 // reuse LDS for cross-wave reduce
  if (lane_col == 0) {
#pragma unroll
    for (int rf = 0; rf < 4; ++rf)
#pragma unroll
      for (int r = 0; r < 4; ++r)
        sbuf[w * 64 + rf * 16 + lane_k8 * 4 + r] = partial[rf][r];
  }
  __syncthreads();
  if (tid < 64) {
    float sc = sbuf[tid] + sbuf[64 + tid] + sbuf[128 + tid] + sbuf[192 + tid];
    scoreW[(size_t)b * NS + s0 + tid] = sc;   // bv omitted: softmax shift-invariant
  }
}

// ---- K3: softmax over S per batch -> attention weights (written to d_out) ----
__global__ void softmax_kernel(const float* __restrict__ scoreW, float* __restrict__ attn) {
  int b = blockIdx.x, tid = threadIdx.x;      // 256 threads
  __shared__ float sred[8];
  const float* sc = scoreW + (size_t)b * NS;
  float m = -3.0e38f;
  for (int s = tid; s < NS; s += 256) m = fmaxf(m, sc[s]);
#pragma unroll
  for (int off = 1; off < 64; off <<= 1) m = fmaxf(m, __shfl_xor(m, off));
  if ((tid & 63) == 0) sred[tid >> 6] = m;
  __syncthreads();
  m = fmaxf(fmaxf(sred[0], sred[1]), fmaxf(sred[2], sred[3]));
  float sum = 0.f;
  for (int s = tid; s < NS; s += 256) sum += __expf(sc[s] - m);
#pragma unroll
  for (int off = 1; off < 64; off <<= 1) sum += __shfl_xor(sum, off);
  if ((tid & 63) == 0) sred[4 + (tid >> 6)] = sum;
  __syncthreads();
  float inv = 1.f / (sred[4] + sred[5] + sred[6] + sred[7]);
  float* ab = attn + (size_t)b * NS;
  for (int s = tid; s < NS; s += 256) ab[s] = __expf(sc[s] - m) * inv;
}

// ---- K4: context partials: ctxpart[b][c][d] = sum_{s in chunk} w[b][s]*values[b][s][d] ----
__global__ void context_partial_kernel(const float* __restrict__ values,
                                       const float* __restrict__ attn,
                                       float* __restrict__ ctxpart) {
  int blk = blockIdx.x;                       // 32 b * 16 chunks
  int b = blk >> 4, c = blk & 15;
  int tid = threadIdx.x;                      // 256
  int t2 = tid & 127;                         // float4 lane within row
  int sg = tid >> 7;                          // 2 s-subgroups
  const float* vb = values + ((size_t)b * NS + c * 256) * ND;
  const float* ab = attn + (size_t)b * NS + c * 256;
  f32x4 acc = {0.f, 0.f, 0.f, 0.f};
  for (int s = sg; s < 256; s += 2) {
    float wv = ab[s];
    f32x4 v = *reinterpret_cast<const f32x4*>(vb + (size_t)s * ND + t2 * 4);
    acc += v * wv;
  }
  __shared__ f32x4 red[128];
  if (sg == 1) red[t2] = acc;
  __syncthreads();
  if (sg == 0) {
    acc += red[t2];
    *reinterpret_cast<f32x4*>(ctxpart + (size_t)blk * ND + t2 * 4) = acc;
  }
}

// ---- K5: reduce 16 chunk-partials -> context_vector (d_out head) ----
__global__ void context_reduce_kernel(const float* __restrict__ ctxpart, float* __restrict__ ctx) {
  int b = blockIdx.x, tid = threadIdx.x;      // 128 threads * float4 = 512
  f32x4 acc = {0.f, 0.f, 0.f, 0.f};
  for (int c = 0; c < 16; ++c)
    acc += *reinterpret_cast<const f32x4*>(ctxpart + (size_t)(b * 16 + c) * ND + tid * 4);
  *reinterpret_cast<f32x4*>(ctx + (size_t)b * ND + tid * 4) = acc;
}

extern "C" void kernel_launch(void* const* d_in, const int* in_sizes, int n_in,
                              void* d_out, int out_size, void* d_ws, size_t ws_size,
                              hipStream_t stream) {
  const float* query  = (const float*)d_in[0];
  const float* values = (const float*)d_in[1];
  const float* W1     = (const float*)d_in[2];
  const float* b1     = (const float*)d_in[3];
  const float* W2     = (const float*)d_in[4];
  const float* b2     = (const float*)d_in[5];
  const float* V      = (const float*)d_in[6];
  // d_in[7] = bv: additive constant on score -> softmax-invariant, score not output: drop.

  float* ctx_out  = (float*)d_out;            // [32][512]
  float* attn_out = ctx_out + NB * ND;        // [32][4096]

  char* ws = (char*)d_ws;                     // ~2.1 MB used
  __bf16* W1f    = (__bf16*)ws;               // 512 KB packed bf16 W1
  float*  pq     = (float*)(ws + 524288);     // 64 KB
  float*  scoreW = (float*)(ws + 589824);     // 512 KB
  float*  ctxp   = (float*)(ws + 1114112);    // 1 MB

  hipLaunchKernelGGL(pack_w1_kernel,        dim3(128),     dim3(256), 0, stream, W1, W1f);
  hipLaunchKernelGGL(proj_query_kernel,     dim3(2, NB),   dim3(256), 0, stream, query, W2, b2, b1, pq);
  hipLaunchKernelGGL(score_kernel,          dim3(2048),    dim3(256), 0, stream, values, W1f, pq, V, scoreW);
  hipLaunchKernelGGL(softmax_kernel,        dim3(NB),      dim3(256), 0, stream, scoreW, attn_out);
  hipLaunchKernelGGL(context_partial_kernel,dim3(NB * 16), dim3(256), 0, stream, values, attn_out, ctxp);
  hipLaunchKernelGGL(context_reduce_kernel, dim3(NB),      dim3(128), 0, stream, ctxp, ctx_out);
}

// Round 2
// 210.095 us; speedup vs baseline: 2.2026x; 2.2026x over previous
//
#include <hip/hip_runtime.h>

// Bahdanau attention, MI355X. B=32, S=4096, D=U=512, fp32 in/out.
// score GEMM (68.7 GFLOP) via bf16 MFMA 16x16x32; proj_v never materialized.
// R2: 8-wave blocks, 32KB K-split double-buffered LDS (occupancy 23->~50%),
//     staging interleaved into MFMA loop, fast tanh (exp-based, branch-free).
#define NB 32
#define NS 4096
#define ND 512
#define NU 512

typedef __attribute__((ext_vector_type(8))) __bf16 bf16x8;
typedef __attribute__((ext_vector_type(8))) short short8;
typedef __attribute__((ext_vector_type(4))) float f32x4;

union Cvt8 { __bf16 h[8]; short8 s8; };

__device__ __forceinline__ float fast_tanh(float x) {
  // tanh(x) = 1 - 2/(exp(2x)+1); v_exp + v_rcp path, saturates correctly at +-inf
  float e = __expf(2.0f * x);
  return 1.0f - __fdividef(2.0f, e + 1.0f);
}

// ---- K0a: pack W1 (f32 [D][U]) -> bf16 MFMA B-fragment order ----
// W1f[ks][ct][lane][j]: k = ks*32 + (lane>>4)*8 + j, u = ct*16 + (lane&15)
__global__ void pack_w1_kernel(const float* __restrict__ W1, __bf16* __restrict__ W1f) {
  int idx = blockIdx.x * 256 + threadIdx.x;   // 0..32767 = [16 ks][32 ct][64 lane]
  int l  = idx & 63;
  int ct = (idx >> 6) & 31;
  int ks = idx >> 11;
  int col   = ct * 16 + (l & 15);
  int kbase = ks * 32 + (l >> 4) * 8;
  Cvt8 u;
#pragma unroll
  for (int j = 0; j < 8; ++j) u.h[j] = (__bf16)W1[(size_t)(kbase + j) * NU + col];
  *reinterpret_cast<short8*>(W1f + (size_t)idx * 8) = u.s8;
}

// ---- K0b: pq[b][u] = query[b]@W2[:,u] + b2[u] + b1[u]  (fp32, tiny) ----
__global__ void proj_query_kernel(const float* __restrict__ query, const float* __restrict__ W2,
                                  const float* __restrict__ b2, const float* __restrict__ b1,
                                  float* __restrict__ pq) {
  int b = blockIdx.y;
  int u = blockIdx.x * 256 + threadIdx.x;
  const float* q = query + (size_t)b * ND;
  float acc = b2[u] + b1[u];
  for (int k = 0; k < ND; ++k) acc += q[k] * W2[(size_t)k * NU + u];
  pq[(size_t)b * NU + u] = acc;
}

// stage one 16KB chunk of a 64x256-k bf16 tile (chunk in 0..3, 512 threads)
__device__ __forceinline__ void stage_chunk(const float* __restrict__ vbase, char* base,
                                            int tid, int kh, int chunk) {
  int idx = chunk * 512 + tid;                // [row 0..63][c8 0..31]
  int row = idx >> 5;
  int c8  = idx & 31;
  const float4* src = reinterpret_cast<const float4*>(vbase + (size_t)row * ND + kh * 256 + c8 * 8);
  float4 f0 = src[0], f1 = src[1];
  Cvt8 u;
  u.h[0] = (__bf16)f0.x; u.h[1] = (__bf16)f0.y; u.h[2] = (__bf16)f0.z; u.h[3] = (__bf16)f0.w;
  u.h[4] = (__bf16)f1.x; u.h[5] = (__bf16)f1.y; u.h[6] = (__bf16)f1.z; u.h[7] = (__bf16)f1.w;
  int boff = row * 512 + ((c8 * 16) ^ ((row & 7) << 4));   // XOR-swizzle (G4/T2)
  *reinterpret_cast<short8*>(base + boff) = u.s8;
}

// ---- K2: score[b][s] = sum_u tanh(values[b,s,:]@W1[:,u] + pq[b][u]) * V[u] ----
// 64 s-rows per block, 8 waves, wave w owns cols [w*64, w*64+64).
// K split in two 256-halves, double-buffered 32KB LDS tiles (bf16, swizzled).
__global__ __launch_bounds__(512, 4)
void score_kernel(const float* __restrict__ values, const __bf16* __restrict__ W1f,
                  const float* __restrict__ pq, const float* __restrict__ V,
                  float* __restrict__ scoreW) {
  __shared__ char ldsb[65536];                // 2 x 32 KB
  char* buf0 = ldsb;
  char* buf1 = ldsb + 32768;

  int bid = blockIdx.x;                       // 2048 = 32 b * 64 tiles
  int b = bid >> 6;
  int s0 = (bid & 63) * 64;
  int tid = threadIdx.x;                      // 512
  int l = tid & 63;
  int w = tid >> 6;                           // 8 waves
  int lane_col = l & 15;
  int lane_k8  = l >> 4;

  const float* vbase = values + ((size_t)b * NS + s0) * ND;
  // B-frag base: element ((kg*32 + w*4+cf)*64 + l)*8
  const __bf16* wptr = W1f + ((size_t)(w * 4) * 64 + l) * 8;

  // prologue: stage k-half 0 into buf0
#pragma unroll
  for (int c = 0; c < 4; ++c) stage_chunk(vbase, buf0, tid, 0, c);
  __syncthreads();

  f32x4 acc[4][4];
#pragma unroll
  for (int rf = 0; rf < 4; ++rf)
#pragma unroll
    for (int cf = 0; cf < 4; ++cf) acc[rf][cf] = (f32x4){0.f, 0.f, 0.f, 0.f};

#pragma unroll
  for (int kh = 0; kh < 2; ++kh) {
    char* rbuf = (kh == 0) ? buf0 : buf1;
#pragma unroll
    for (int ks = 0; ks < 8; ++ks) {
      if (kh == 0 && ks < 4) stage_chunk(vbase, buf1, tid, 1, ks);  // overlap next-half stage
      bf16x8 a[4];
      int kbyte = ks * 64 + lane_k8 * 16;
#pragma unroll
      for (int rf = 0; rf < 4; ++rf) {
        int row = rf * 16 + lane_col;
        a[rf] = *reinterpret_cast<const bf16x8*>(rbuf + row * 512 + (kbyte ^ ((row & 7) << 4)));
      }
      int kg = kh * 8 + ks;
      bf16x8 bb[4];
#pragma unroll
      for (int cf = 0; cf < 4; ++cf)
        bb[cf] = *reinterpret_cast<const bf16x8*>(wptr + (size_t)kg * 16384 + cf * 512);
#pragma unroll
      for (int cf = 0; cf < 4; ++cf)
#pragma unroll
        for (int rf = 0; rf < 4; ++rf)
          acc[rf][cf] = __builtin_amdgcn_mfma_f32_16x16x32_bf16(a[rf], bb[cf], acc[rf][cf], 0, 0, 0);
    }
    if (kh == 0) __syncthreads();             // buf1 staged & buf0 reads done
  }

  // epilogue: tanh(proj + pq) * V, accumulate per-row partials
  float partial[4][4];
#pragma unroll
  for (int rf = 0; rf < 4; ++rf)
#pragma unroll
    for (int r = 0; r < 4; ++r) partial[rf][r] = 0.f;

  const float* pqb = pq + (size_t)b * NU;
#pragma unroll
  for (int cf = 0; cf < 4; ++cf) {
    int col = w * 64 + cf * 16 + lane_col;    // C/D: col = lane&15 (m89-verified)
    float pqv = pqb[col];
    float Vv  = V[col];
#pragma unroll
    for (int rf = 0; rf < 4; ++rf)
#pragma unroll
      for (int r = 0; r < 4; ++r)
        partial[rf][r] += fast_tanh(acc[rf][cf][r] + pqv) * Vv;
  }

  // reduce over the 16 cols held across lanes sharing l>>4 (bits 0..3 of lane)
#pragma unroll
  for (int off = 1; off < 16; off <<= 1)
#pragma unroll
    for (int rf = 0; rf < 4; ++rf)
#pragma unroll
      for (int r = 0; r < 4; ++r) partial[rf][r] += __shfl_xor(partial[rf][r], off);

  // cross-wave reduce via LDS (buf0 region is dead: last read before kh=1 barrier)
  float* sbuf = (float*)ldsb;                 // [8 waves][64 rows]
  if (lane_col == 0) {
#pragma unroll
    for (int rf = 0; rf < 4; ++rf)
#pragma unroll
      for (int r = 0; r < 4; ++r)
        sbuf[w * 64 + rf * 16 + lane_k8 * 4 + r] = partial[rf][r];
  }
  __syncthreads();
  if (tid < 64) {
    float sc = 0.f;
#pragma unroll
    for (int wv = 0; wv < 8; ++wv) sc += sbuf[wv * 64 + tid];
    scoreW[(size_t)b * NS + s0 + tid] = sc;   // bv omitted: softmax shift-invariant
  }
}

// ---- K3: softmax over S per batch -> attention weights (written to d_out) ----
__global__ void softmax_kernel(const float* __restrict__ scoreW, float* __restrict__ attn) {
  int b = blockIdx.x, tid = threadIdx.x;      // 256 threads
  __shared__ float sred[8];
  const float* sc = scoreW + (size_t)b * NS;
  float m = -3.0e38f;
  for (int s = tid; s < NS; s += 256) m = fmaxf(m, sc[s]);
#pragma unroll
  for (int off = 1; off < 64; off <<= 1) m = fmaxf(m, __shfl_xor(m, off));
  if ((tid & 63) == 0) sred[tid >> 6] = m;
  __syncthreads();
  m = fmaxf(fmaxf(sred[0], sred[1]), fmaxf(sred[2], sred[3]));
  float sum = 0.f;
  for (int s = tid; s < NS; s += 256) sum += __expf(sc[s] - m);
#pragma unroll
  for (int off = 1; off < 64; off <<= 1) sum += __shfl_xor(sum, off);
  if ((tid & 63) == 0) sred[4 + (tid >> 6)] = sum;
  __syncthreads();
  float inv = 1.f / (sred[4] + sred[5] + sred[6] + sred[7]);
  float* ab = attn + (size_t)b * NS;
  for (int s = tid; s < NS; s += 256) ab[s] = __expf(sc[s] - m) * inv;
}

// ---- K4: context partials: ctxpart[b][c][d] = sum_{s in chunk} w[b][s]*values[b][s][d] ----
__global__ void context_partial_kernel(const float* __restrict__ values,
                                       const float* __restrict__ attn,
                                       float* __restrict__ ctxpart) {
  int blk = blockIdx.x;                       // 32 b * 16 chunks
  int b = blk >> 4, c = blk & 15;
  int tid = threadIdx.x;                      // 256
  int t2 = tid & 127;                         // float4 lane within row
  int sg = tid >> 7;                          // 2 s-subgroups
  const float* vb = values + ((size_t)b * NS + c * 256) * ND;
  const float* ab = attn + (size_t)b * NS + c * 256;
  f32x4 acc = {0.f, 0.f, 0.f, 0.f};
  for (int s = sg; s < 256; s += 2) {
    float wv = ab[s];
    f32x4 v = *reinterpret_cast<const f32x4*>(vb + (size_t)s * ND + t2 * 4);
    acc += v * wv;
  }
  __shared__ f32x4 red[128];
  if (sg == 1) red[t2] = acc;
  __syncthreads();
  if (sg == 0) {
    acc += red[t2];
    *reinterpret_cast<f32x4*>(ctxpart + (size_t)blk * ND + t2 * 4) = acc;
  }
}

// ---- K5: reduce 16 chunk-partials -> context_vector (d_out head) ----
__global__ void context_reduce_kernel(const float* __restrict__ ctxpart, float* __restrict__ ctx) {
  int b = blockIdx.x, tid = threadIdx.x;      // 128 threads * float4 = 512
  f32x4 acc = {0.f, 0.f, 0.f, 0.f};
  for (int c = 0; c < 16; ++c)
    acc += *reinterpret_cast<const f32x4*>(ctxpart + (size_t)(b * 16 + c) * ND + tid * 4);
  *reinterpret_cast<f32x4*>(ctx + (size_t)b * ND + tid * 4) = acc;
}

extern "C" void kernel_launch(void* const* d_in, const int* in_sizes, int n_in,
                              void* d_out, int out_size, void* d_ws, size_t ws_size,
                              hipStream_t stream) {
  const float* query  = (const float*)d_in[0];
  const float* values = (const float*)d_in[1];
  const float* W1     = (const float*)d_in[2];
  const float* b1     = (const float*)d_in[3];
  const float* W2     = (const float*)d_in[4];
  const float* b2     = (const float*)d_in[5];
  const float* V      = (const float*)d_in[6];
  // d_in[7] = bv: additive constant on score -> softmax-invariant, score not output: drop.

  float* ctx_out  = (float*)d_out;            // [32][512]
  float* attn_out = ctx_out + NB * ND;        // [32][4096]

  char* ws = (char*)d_ws;                     // ~2.1 MB used
  __bf16* W1f    = (__bf16*)ws;               // 512 KB packed bf16 W1
  float*  pq     = (float*)(ws + 524288);     // 64 KB
  float*  scoreW = (float*)(ws + 589824);     // 512 KB
  float*  ctxp   = (float*)(ws + 1114112);    // 1 MB

  hipLaunchKernelGGL(pack_w1_kernel,        dim3(128),     dim3(256), 0, stream, W1, W1f);
  hipLaunchKernelGGL(proj_query_kernel,     dim3(2, NB),   dim3(256), 0, stream, query, W2, b2, b1, pq);
  hipLaunchKernelGGL(score_kernel,          dim3(2048),    dim3(512), 0, stream, values, W1f, pq, V, scoreW);
  hipLaunchKernelGGL(softmax_kernel,        dim3(NB),      dim3(256), 0, stream, scoreW, attn_out);
  hipLaunchKernelGGL(context_partial_kernel,dim3(NB * 16), dim3(256), 0, stream, values, attn_out, ctxp);
  hipLaunchKernelGGL(context_reduce_kernel, dim3(NB),      dim3(128), 0, stream, ctxp, ctx_out);
}